// Round 2
// baseline (379.707 us; speedup 1.0000x reference)
//
#include <hip/hip_runtime.h>

// Problem: B=2048, H=4, D=4096, M=8, dm=512.
// s_flat[r,j] = sum_h x[b,h,m*512+c]*lW[m,h] + lb[m],
//   m=r>>8, b=(r&255)*8+(j>>9), c=j&511.
// out[r,n] = sigmoid(sum_j s_flat[r,j]*pW[n,j] + pb[n]),  out fp32 [2048][4096].
//
// R6: keep s-only prep (R5's win: prep 85.7 -> ~50 us). Fix R5's gemm
// regression (137 us, MfmaUtil 20.8%): the B32-LDS-round-trip cvt phase
// (~8 ds_read + ~130 VALU + 4 ds_write serial between barriers) is replaced by
//   (a) reg-staged W fp32 (8x global_load_dwordx4, issued one tile ahead) +
//       native __bf16 casts (compiler fuses to v_cvt_pk_bf16_f32) +
//       4 swizzled ds_write_b128  -- removes LDS round trip and ~100 VALU/tile;
//   (b) double-buffered As/Bs with ONE __syncthreads per K-tile: loads for
//       tile kt+1 are issued right after barrier(kt) and fly under MFMA(kt),
//       drained by barrier(kt+1)'s implicit vmcnt(0) (T14 issue-early).

#define MD 2048
#define ND 4096
#define KD 4096

typedef __attribute__((ext_vector_type(8))) __bf16 bf16x8;
typedef __attribute__((ext_vector_type(4))) float f32x4;

static __device__ __forceinline__ unsigned int f2bf(float f) {
  union { float f; unsigned int u; } v; v.f = f;
  unsigned int u = v.u;
  u += 0x7FFFu + ((u >> 16) & 1u);   // RNE
  return u >> 16;
}

// pack two floats -> 2x bf16 in a dword via native __bf16 casts (RNE; compiler
// emits v_cvt_pk_bf16_f32 for pairs -- m240: casts beat hand-written cvt)
static __device__ __forceinline__ unsigned int pk2bf(float a, float b) {
  union { __bf16 h; unsigned short u; } x, y;
  x.h = (__bf16)a; y.h = (__bf16)b;
  return (unsigned)x.u | ((unsigned)y.u << 16);
}

// Prep v4 (unchanged from R5): s_flat only. One-shot threads, 8x16B loads in
// flight, plain cacheable loads, 16B stores. Grid 4096 blocks.
__global__ __launch_bounds__(256) void prep_kernel(
    const float* __restrict__ x, const float* __restrict__ lW,
    const float* __restrict__ lb, unsigned short* __restrict__ sB) {
  int g = blockIdx.x * 256 + threadIdx.x;   // 0 .. 2^20
  int j8 = g << 3;                          // flat index r*4096 + j, j8 % 8 == 0
  int r = j8 >> 12;
  int j = j8 & 4095;
  int m = r >> 8;
  int b = ((r & 255) << 3) + (j >> 9);
  int c = j & 511;                          // 8 consecutive j stay in one 512-group
  const float* xp = x + ((long)b << 14) + m * 512 + c;
  float w0 = lW[m * 4 + 0], w1 = lW[m * 4 + 1], w2 = lW[m * 4 + 2], w3 = lW[m * 4 + 3];
  float bb = lb[m];
  float4 xa0 = *(const float4*)(xp);
  float4 xb0 = *(const float4*)(xp + 4);
  float4 xa1 = *(const float4*)(xp + 4096);
  float4 xb1 = *(const float4*)(xp + 4100);
  float4 xa2 = *(const float4*)(xp + 8192);
  float4 xb2 = *(const float4*)(xp + 8196);
  float4 xa3 = *(const float4*)(xp + 12288);
  float4 xb3 = *(const float4*)(xp + 12292);
  float v0 = bb + xa0.x * w0 + xa1.x * w1 + xa2.x * w2 + xa3.x * w3;
  float v1 = bb + xa0.y * w0 + xa1.y * w1 + xa2.y * w2 + xa3.y * w3;
  float v2 = bb + xa0.z * w0 + xa1.z * w1 + xa2.z * w2 + xa3.z * w3;
  float v3 = bb + xa0.w * w0 + xa1.w * w1 + xa2.w * w2 + xa3.w * w3;
  float v4 = bb + xb0.x * w0 + xb1.x * w1 + xb2.x * w2 + xb3.x * w3;
  float v5 = bb + xb0.y * w0 + xb1.y * w1 + xb2.y * w2 + xb3.y * w3;
  float v6 = bb + xb0.z * w0 + xb1.z * w1 + xb2.z * w2 + xb3.z * w3;
  float v7 = bb + xb0.w * w0 + xb1.w * w1 + xb2.w * w2 + xb3.w * w3;
  uint4 pk;
  pk.x = f2bf(v0) | (f2bf(v1) << 16);
  pk.y = f2bf(v2) | (f2bf(v3) << 16);
  pk.z = f2bf(v4) | (f2bf(v5) << 16);
  pk.w = f2bf(v6) | (f2bf(v7) << 16);
  *(uint4*)(sB + j8) = pk;                  // 16B store
}

// GEMM: C[2048][4096] = S[2048][4096] * W[4096][4096]^T, S bf16, W fp32
// (converted to bf16 in registers during staging), epilogue sigmoid(acc+pb).
// 128x128 block tile, BK=64, 4 waves 2x2, each wave 4x4 of 16x16x32 MFMA.
//
// LDS: As/Bs double-buffered bf16 [row][64] ushorts, 64 KiB total, XOR
// 16B-chunk swizzle (phys chunk = kc ^ (row&7)):
//   As: filled by global_load_lds with the swizzle pre-applied to the per-lane
//       GLOBAL source address (linear LDS dest -- m173 pattern, proven R0).
//   Bs: filled by ds_write_b128 of reg-converted W (write-side applies the
//       same swizzle). Fragment-read side identical to R0 (bank-conflict 0).
#define BM 128
#define BN 128
#define BK 64

__global__ __launch_bounds__(256) void gemm_kernel(
    const unsigned short* __restrict__ S, const float* __restrict__ W,
    const float* __restrict__ pb, float* __restrict__ out) {
  __shared__ unsigned short As[2][BM * BK];   // 2 x 16 KiB
  __shared__ unsigned short Bs[2][BN * BK];   // 2 x 16 KiB
  int tid = threadIdx.x;
  int lane = tid & 63;
  int wave = tid >> 6;
  int n0 = blockIdx.x * BN;   // 32 n-tiles
  int r0 = blockIdx.y * BM;   // 16 m-tiles
  int wr = wave >> 1, wc = wave & 1;

  // ---- A staging (global_load_lds, src-swizzled, linear dest)
  int srow = (wave << 5) + (lane >> 3);            // + i*8 per issue
  int scol = (((lane & 7) ^ (lane >> 3)) << 3);    // swizzled k-element offset
  const unsigned short* gA = S + (long)(r0 + srow) * KD + scol;
  int lAoff = (wave << 5) * BK;   // wave-uniform LDS base; HW adds lane*16B

  // ---- W reg-staging: thread -> row = tid>>1, k-half = tid&1 (32 consec k).
  // Lane pairs share a row (two 16B slots in a 256B span -> 32B/line merge).
  int brow = tid >> 1;
  int bk0 = (tid & 1) << 5;
  const float* gW = W + (long)(n0 + brow) * KD + bk0;
  unsigned short* bs0 = &Bs[0][brow * BK];
  unsigned short* bs1 = &Bs[1][brow * BK];
  int bsw = brow & 7;
  int kcb = (tid & 1) << 2;     // chunk base: kc = kcb + q2

  f32x4 acc[4][4] = {};
  f32x4 wv[8];                  // W fp32 in flight (32 VGPR), one tile ahead

  // prologue: issue A(0) -> As[0] and W(0) -> regs
#pragma unroll
  for (int i = 0; i < 4; ++i)
    __builtin_amdgcn_global_load_lds(
        (const __attribute__((address_space(1))) unsigned int*)(gA + (long)i * 8 * KD),
        (__attribute__((address_space(3))) unsigned int*)(&As[0][lAoff + i * 8 * BK]), 16, 0, 0);
#pragma unroll
  for (int q = 0; q < 8; ++q)
    wv[q] = *(const f32x4*)(gW + q * 4);

  for (int kt = 0; kt < KD; kt += BK) {
    int cur = (kt >> 6) & 1;
    // ---- cvt W(kt) regs -> Bs[cur] (waits on wv vmcnt; ~16 cvt_pk + 4 writes)
    unsigned short* bs = cur ? bs1 : bs0;
#pragma unroll
    for (int q2 = 0; q2 < 4; ++q2) {
      f32x4 u = wv[2 * q2], v = wv[2 * q2 + 1];
      uint4 pk;
      pk.x = pk2bf(u[0], u[1]);
      pk.y = pk2bf(u[2], u[3]);
      pk.z = pk2bf(v[0], v[1]);
      pk.w = pk2bf(v[2], v[3]);
      *(uint4*)&bs[((kcb + q2) ^ bsw) << 3] = pk;   // balanced banks: no conflict
    }
    __syncthreads();   // drains A(kt) gload_lds (vmcnt0) + publishes Bs[cur] (lgkm0)
    // ---- issue staging for kt+BK: flies under the MFMA phase below,
    // drained at barrier(kt+BK). As[nxt]'s last readers finished pre-barrier.
    if (kt + BK < KD) {
      int nxt = cur ^ 1;
#pragma unroll
      for (int i = 0; i < 4; ++i)
        __builtin_amdgcn_global_load_lds(
            (const __attribute__((address_space(1))) unsigned int*)(gA + (long)i * 8 * KD + kt + BK),
            (__attribute__((address_space(3))) unsigned int*)(&As[nxt][lAoff + i * 8 * BK]), 16, 0, 0);
#pragma unroll
      for (int q = 0; q < 8; ++q)
        wv[q] = *(const f32x4*)(gW + kt + BK + q * 4);
    }
    // ---- MFMA phase on As[cur]/Bs[cur]
#pragma unroll
    for (int ks = 0; ks < 2; ++ks) {
      // fragment chunk kc_lin = ks*4 + (lane>>4); physical chunk =
      // kc_lin ^ (row & 7); row&7 == lane&7 for all t (t*16 is 0 mod 8).
      int swz = (((ks << 2) + (lane >> 4)) ^ (lane & 7)) << 3;
      bf16x8 af[4], bfr[4];
#pragma unroll
      for (int t = 0; t < 4; ++t) {
        af[t]  = *(const bf16x8*)&As[cur][((wr << 6) + t * 16 + (lane & 15)) * BK + swz];
        bfr[t] = *(const bf16x8*)&Bs[cur][((wc << 6) + t * 16 + (lane & 15)) * BK + swz];
      }
#pragma unroll
      for (int mt = 0; mt < 4; ++mt)
#pragma unroll
        for (int nt = 0; nt < 4; ++nt)
          acc[mt][nt] = __builtin_amdgcn_mfma_f32_16x16x32_bf16(af[mt], bfr[nt], acc[mt][nt], 0, 0, 0);
    }
  }

  // epilogue: C/D layout col=lane&15, row=(lane>>4)*4+i  [m89/m91]
#pragma unroll
  for (int nt = 0; nt < 4; ++nt) {
    int col = n0 + (wc << 6) + nt * 16 + (lane & 15);
    float pbv = pb[col];
#pragma unroll
    for (int mt = 0; mt < 4; ++mt) {
      int row = r0 + (wr << 6) + mt * 16 + ((lane >> 4) << 2);
#pragma unroll
      for (int i = 0; i < 4; ++i) {
        float v = acc[mt][nt][i] + pbv;
        out[(long)(row + i) * ND + col] = 1.0f / (1.0f + __expf(-v));
      }
    }
  }
}

extern "C" void kernel_launch(void* const* d_in, const int* in_sizes, int n_in,
                              void* d_out, int out_size, void* d_ws, size_t ws_size,
                              hipStream_t stream) {
  const float* x  = (const float*)d_in[0];   // (2048, 4, 4096)
  const float* lW = (const float*)d_in[1];   // (8, 4)
  const float* lb = (const float*)d_in[2];   // (8,)
  const float* pW = (const float*)d_in[3];   // (4096, 4096)
  const float* pb = (const float*)d_in[4];   // (4096,)
  float* out = (float*)d_out;                // (2048, 4096) fp32

  unsigned short* sB = (unsigned short*)d_ws;          // 2048*4096 bf16 = 16 MiB

  prep_kernel<<<4096, 256, 0, stream>>>(x, lW, lb, sB);
  gemm_kernel<<<dim3(32, 16), 256, 0, stream>>>(sB, pW, pb, out);
}